// Round 5
// baseline (126.851 us; speedup 1.0000x reference)
//
#include <hip/hip_runtime.h>
#include <hip/hip_bf16.h>
#include <math.h>

#define BB 16
#define SS 2048
#define DM 384
#define DQ 64
#define M_ROWS (BB * SS)   // 32768

typedef short short8 __attribute__((ext_vector_type(8)));
typedef float f32x4  __attribute__((ext_vector_type(4)));

// ws layout (in shorts / bf16 elements):
//   Wt  [3*64][384]  (W transposed: row = mat*64+n, col = k)   73728
//   Qb  [B][S][64]   (Q * 0.125 * log2e, bf16)                 2097152
//   Kb  [B][S][64]                                             2097152
//   Vt  [B][64][S]   (V transposed per batch)                  2097152
#define WT_OFF 0
#define QB_OFF 73728
#define KB_OFF (QB_OFF + M_ROWS * DQ)
#define VT_OFF (KB_OFF + M_ROWS * DQ)

#define QSCALE 0.18033688011112042f   // 0.125 * log2(e); softmax done in exp2

// fp32 -> bf16 round-to-nearest-even
__device__ __forceinline__ short f2bf(float f) {
  unsigned u = __builtin_bit_cast(unsigned, f);
  unsigned r = (u + 0x7fffu + ((u >> 16) & 1u)) >> 16;
  return (short)r;
}
__device__ __forceinline__ unsigned pack2bf(float a, float b) {
  return (unsigned)(unsigned short)f2bf(a) |
         ((unsigned)(unsigned short)f2bf(b) << 16);
}
// async 16B global -> LDS (LDS dest = wave-uniform base + lane*16)
__device__ __forceinline__ void async16(const short* g, short* l) {
  __builtin_amdgcn_global_load_lds(
      (const __attribute__((address_space(1))) unsigned int*)g,
      (__attribute__((address_space(3))) unsigned int*)l, 16, 0, 0);
}

// ---------------------------------------------------------------------------
// Kernel 0: W [384,64] fp32 x3 -> Wt rows [mat*64+n][384] bf16.  288 x 256.
// ---------------------------------------------------------------------------
__global__ void prep_w_kernel(const float* __restrict__ Wq,
                              const float* __restrict__ Wk,
                              const float* __restrict__ Wv,
                              short* __restrict__ ws) {
  int o = blockIdx.x * 256 + threadIdx.x;        // 0 .. 73727
  int mat = o / (DM * DQ);
  int r = o % (DM * DQ);
  int k = r / DQ, n = r % DQ;                    // coalesced read
  const float* W = (mat == 0) ? Wq : (mat == 1) ? Wk : Wv;
  ws[WT_OFF + mat * (DM * DQ) + n * DM + k] = f2bf(W[k * DQ + n]);
}

// ---------------------------------------------------------------------------
// Kernel 1: QKV projection, bf16 MFMA 16x16x32, SOFTWARE-PIPELINED.
// Wt chunks double-buffered in LDS; x reg-prefetched one K-iter ahead.
// Steady state: barrier drains loads issued a full compute phase ago.
// Block: 64 rows x 192 cols, 256 thr = 4 waves x 16 rows.  grid 512.
// ---------------------------------------------------------------------------
__global__ __launch_bounds__(256) void qkv_proj_mfma(
    const float* __restrict__ x, const short* __restrict__ ws_r,
    short* __restrict__ ws_w) {
  __shared__ short Wtc[2][12288];   // [buf][row*64 + (gr^(row&7))*8]
  __shared__ short Ep[64 * 200];    // epilogue transpose (200*2B = 25*16B)
  const int tid = threadIdx.x;
  const int lane = tid & 63, w = tid >> 6;
  const int cidx = lane & 15, g = lane >> 4;
  const int g8 = g * 8, g4 = g * 4;
  const int sw7 = cidx & 7;
  const int rows0 = blockIdx.x * 64;
  const short* Wt = ws_r + WT_OFF;

  // staging address precompute: issue itr covers rows itr*32..itr*32+31
  const int prow = tid >> 3;              // 0..31
  const int pgr = tid & 7;
  const short* wsrc = Wt + (size_t)prow * DM + ((pgr ^ (prow & 7)) * 8);

  f32x4 acc[12];
  #pragma unroll
  for (int i = 0; i < 12; ++i) acc[i] = (f32x4){0.f, 0.f, 0.f, 0.f};

  const float* xr = x + (size_t)(rows0 + 16 * w + cidx) * DM;

  // preamble: x chunk 0 into regs, Wt chunk 0 into buf 0
  float4 xc0 = *(const float4*)(xr + g8);
  float4 xc1 = *(const float4*)(xr + g8 + 4);
  float4 xc2 = *(const float4*)(xr + 32 + g8);
  float4 xc3 = *(const float4*)(xr + 32 + g8 + 4);
  #pragma unroll
  for (int itr = 0; itr < 6; ++itr)
    async16(wsrc + (size_t)itr * 32 * DM, &Wtc[0][(itr * 256 + w * 64) * 8]);

  #pragma unroll
  for (int it = 0; it < 6; ++it) {
    __syncthreads();   // drains: Wt chunk `it` + x regs for `it` (issued it-1)

    float4 xn0, xn1, xn2, xn3;
    if (it < 5) {
      const int k0n = (it + 1) * 64;
      #pragma unroll
      for (int itr = 0; itr < 6; ++itr)
        async16(wsrc + (size_t)itr * 32 * DM + k0n,
                &Wtc[(it + 1) & 1][(itr * 256 + w * 64) * 8]);
      xn0 = *(const float4*)(xr + k0n + g8);
      xn1 = *(const float4*)(xr + k0n + g8 + 4);
      xn2 = *(const float4*)(xr + k0n + 32 + g8);
      xn3 = *(const float4*)(xr + k0n + 32 + g8 + 4);
    }

    short8 a0, a1;
    a0[0]=f2bf(xc0.x); a0[1]=f2bf(xc0.y); a0[2]=f2bf(xc0.z); a0[3]=f2bf(xc0.w);
    a0[4]=f2bf(xc1.x); a0[5]=f2bf(xc1.y); a0[6]=f2bf(xc1.z); a0[7]=f2bf(xc1.w);
    a1[0]=f2bf(xc2.x); a1[1]=f2bf(xc2.y); a1[2]=f2bf(xc2.z); a1[3]=f2bf(xc2.w);
    a1[4]=f2bf(xc3.x); a1[5]=f2bf(xc3.y); a1[6]=f2bf(xc3.z); a1[7]=f2bf(xc3.w);

    const short* Wb = Wtc[it & 1];
    #pragma unroll
    for (int ct = 0; ct < 12; ++ct) {
      int row = ct * 16 + cidx;
      short8 b0 = *(const short8*)&Wb[row * 64 + ((g ^ sw7) * 8)];
      short8 b1 = *(const short8*)&Wb[row * 64 + (((g + 4) ^ sw7) * 8)];
      acc[ct] = __builtin_amdgcn_mfma_f32_16x16x32_bf16(a0, b0, acc[ct], 0, 0, 0);
      acc[ct] = __builtin_amdgcn_mfma_f32_16x16x32_bf16(a1, b1, acc[ct], 0, 0, 0);
    }
    if (it < 5) { xc0 = xn0; xc1 = xn1; xc2 = xn2; xc3 = xn3; }
  }

  // ---- epilogue: transpose through Ep, vector stores ----
  __syncthreads();
  const int erow = 16 * w + g4;
  #pragma unroll
  for (int ct = 0; ct < 4; ++ct)
    #pragma unroll
    for (int r = 0; r < 4; ++r) {
      Ep[(erow + r) * 200 + ct * 16 + cidx]       = f2bf(acc[ct][r] * QSCALE);
      Ep[(erow + r) * 200 + 64 + ct * 16 + cidx]  = f2bf(acc[4 + ct][r]);
      Ep[(ct * 16 + cidx) * 200 + 128 + erow + r] = f2bf(acc[8 + ct][r]);
    }
  __syncthreads();

  short* Qb = ws_w + QB_OFF;
  short* Kb = ws_w + KB_OFF;
  short* Vt = ws_w + VT_OFF;
  const int bidx = rows0 >> 11;
  const int srow0 = rows0 & 2047;
  #pragma unroll
  for (int t2 = 0; t2 < 2; ++t2) {
    int i = t2 * 256 + tid;            // 0..511
    int row = i >> 3, gq = i & 7;
    *(short8*)&Qb[(size_t)(rows0 + row) * DQ + gq * 8] =
        *(const short8*)&Ep[row * 200 + gq * 8];
    *(short8*)&Kb[(size_t)(rows0 + row) * DQ + gq * 8] =
        *(const short8*)&Ep[row * 200 + 64 + gq * 8];
    *(short8*)&Vt[(size_t)bidx * (64 * SS) + (size_t)row * SS + srow0 + gq * 8] =
        *(const short8*)&Ep[row * 200 + 128 + gq * 8];   // row = d here
  }
}

// ---------------------------------------------------------------------------
// Kernel 2: causal flash attention, transposed-S MFMA, static-max softmax,
// SOFTWARE-PIPELINED K/V double buffer.
// 64-key supersteps; K/V tiles double-buffered (4x8KB); barrier at top of
// superstep i drains the prefetch issued during superstep i-1 -> staging
// latency hidden behind a full compute phase.
// Block: 256 thr = 4 waves = 2 q-groups (16 q) x 2 key-splits (32 k each).
// LDS 37 KB -> 4 blocks/CU; grid (64,16) = 1024 = all resident, balanced.
// ---------------------------------------------------------------------------
__global__ __launch_bounds__(256, 4) void flash_mfma(
    const short* __restrict__ ws, float* __restrict__ O) {
  __shared__ short smem[18944];           // 37 KiB
  // [0..4095] KsA, [4096..8191] KsB, [8192..12287] VtsA, [12288..16383] VtsB,
  // [16384..18943] Ps (4 waves x 16q x 40)
  const int b = blockIdx.y;
  const int qt = (b < 8) ? (63 - (int)blockIdx.x) : (int)blockIdx.x;
  const int q0 = qt * 32;
  const int tid = threadIdx.x;
  const int lane = tid & 63, w = tid >> 6;
  const int qg = w & 1, s = w >> 1;
  const int cidx = lane & 15, g = lane >> 4;
  const int g8 = g * 8, g4 = g * 4;
  const int sw7 = cidx & 7;
  short* Ps = smem + 16384 + w * 640;     // [16 q][40] per wave

  const short* Qb = ws + QB_OFF + (size_t)b * SS * DQ;
  const short* Kb = ws + KB_OFF + (size_t)b * SS * DQ;
  const short* Vt = ws + VT_OFF + (size_t)b * 64 * SS;

  const int qrow = q0 + qg * 16;
  const int qglob = qrow + cidx;          // this lane's query
  short8 qf0 = *(const short8*)&Qb[(size_t)qglob * DQ + g8];
  short8 qf1 = *(const short8*)&Qb[(size_t)qglob * DQ + 32 + g8];

  // staging bases: issue t covers rows t*32..t*32+31; (row+32)&7 == row&7
  const int srow = tid >> 3;              // 0..31
  const int sgr = tid & 7;
  const int ssw = (sgr ^ (srow & 7)) * 8;
  const short* kb0 = Kb + (size_t)srow * DQ + ssw;
  const short* kb1 = Kb + (size_t)(srow + 32) * DQ + ssw;
  const short* vb0 = Vt + (size_t)srow * SS + ssw;
  const short* vb1 = Vt + (size_t)(srow + 32) * SS + ssw;
  const int dst0 = (w * 64) * 8, dst1 = (256 + w * 64) * 8;

  f32x4 o[4];
  #pragma unroll
  for (int i = 0; i < 4; ++i) o[i] = (f32x4){0.f, 0.f, 0.f, 0.f};
  float l = 0.f;

  const int nss = (qt >> 1) + 1;          // 64-key supersteps

  // preamble: stage superstep 0 into buffer 0
  async16(kb0, &smem[dst0]);
  async16(kb1, &smem[dst1]);
  async16(vb0, &smem[8192 + dst0]);
  async16(vb1, &smem[8192 + dst1]);

  for (int ssi = 0; ssi < nss; ++ssi) {
    __syncthreads();   // drains prefetch of ss `ssi` (issued last iteration)

    {   // prefetch ss+1 into the other buffer (clamped source, always issued)
      int nb = (ssi + 1) * 64;
      if (nb > SS - 64) nb = SS - 64;
      const int nbuf = ((ssi + 1) & 1) * 4096;
      const size_t koff = (size_t)nb * DQ;
      async16(kb0 + koff, &smem[nbuf + dst0]);
      async16(kb1 + koff, &smem[nbuf + dst1]);
      async16(vb0 + nb, &smem[8192 + nbuf + dst0]);
      async16(vb1 + nb, &smem[8192 + nbuf + dst1]);
    }

    const int kt32 = ssi * 2 + s;
    if (kt32 <= qt) {
      const short* Kc = smem + (ssi & 1) * 4096;
      const short* Vc = smem + 8192 + (ssi & 1) * 4096;
      const int kbase = ssi * 64;
      // S^T = K Q^T  (each lane: 8 scores of query `qglob`)
      f32x4 sc[2];
      #pragma unroll
      for (int ct = 0; ct < 2; ++ct) {
        int krow = s * 32 + ct * 16 + cidx;
        short8 kf0 = *(const short8*)&Kc[krow * 64 + ((g ^ sw7) * 8)];
        short8 kf1 = *(const short8*)&Kc[krow * 64 + (((g + 4) ^ sw7) * 8)];
        f32x4 a = (f32x4){0.f, 0.f, 0.f, 0.f};
        a = __builtin_amdgcn_mfma_f32_16x16x32_bf16(kf0, qf0, a, 0, 0, 0);
        a = __builtin_amdgcn_mfma_f32_16x16x32_bf16(kf1, qf1, a, 0, 0, 0);
        sc[ct] = a;
      }
      if (kt32 == qt) {                   // diagonal: mask key > q
        #pragma unroll
        for (int ct = 0; ct < 2; ++ct) {
          int key = kbase + s * 32 + ct * 16 + g4;
          #pragma unroll
          for (int r = 0; r < 4; ++r)
            if (key + r > qglob) sc[ct][r] = -1e30f;
        }
      }
      // static-max softmax: p = 2^s, per-lane l, no rescale
      #pragma unroll
      for (int ct = 0; ct < 2; ++ct) {
        #pragma unroll
        for (int r = 0; r < 4; ++r) {
          float p = __builtin_amdgcn_exp2f(sc[ct][r]);
          sc[ct][r] = p;
          l += p;
        }
        uint2 pk;
        pk.x = pack2bf(sc[ct][0], sc[ct][1]);
        pk.y = pack2bf(sc[ct][2], sc[ct][3]);
        *(uint2*)&Ps[cidx * 40 + ct * 16 + g4] = pk;
      }
      // O^T += V^T P^T  (one K=32 MFMA per d-tile)
      short8 pf = *(const short8*)&Ps[cidx * 40 + g8];
      #pragma unroll
      for (int dt = 0; dt < 4; ++dt) {
        int vrow = dt * 16 + cidx;
        short8 vf = *(const short8*)&Vc[vrow * 64 + (((s * 4 + g) ^ sw7) * 8)];
        o[dt] = __builtin_amdgcn_mfma_f32_16x16x32_bf16(vf, pf, o[dt], 0, 0, 0);
      }
    }
  }

  // reduce l across the 4 row-groups (query q's scores sit in lanes
  // {q, q+16, q+32, q+48}) — once, not per superstep
  l += __shfl_xor(l, 16);
  l += __shfl_xor(l, 32);

  // ---- combine the two key-splits (plain sums), normalize, store ----
  float* o1x = (float*)smem;              // 2048 f32 (8 KB)
  float* l1x = (float*)(smem + 4096);     // 32 f32
  float* Of  = (float*)(smem + 4224);     // [32][72] f32
  __syncthreads();
  if (s == 1) {
    int base = qg * 1024;
    #pragma unroll
    for (int dt = 0; dt < 4; ++dt)
      #pragma unroll
      for (int r = 0; r < 4; ++r)
        o1x[base + dt * 256 + r * 64 + lane] = o[dt][r];
    if (g == 0) l1x[qg * 16 + cidx] = l;
  }
  __syncthreads();
  if (s == 0) {
    int base = qg * 1024;
    float inv = 1.0f / (l + l1x[qg * 16 + cidx]);
    #pragma unroll
    for (int dt = 0; dt < 4; ++dt)
      #pragma unroll
      for (int r = 0; r < 4; ++r)
        Of[(qg * 16 + cidx) * 72 + dt * 16 + g4 + r] =
            (o[dt][r] + o1x[base + dt * 256 + r * 64 + lane]) * inv;
  }
  __syncthreads();
  #pragma unroll
  for (int t2 = 0; t2 < 2; ++t2) {        // 32 q x 16 float4 = 512 / 256 thr
    int i = t2 * 256 + tid;
    int qb = i >> 4, f4 = i & 15;
    float4 v = *(const float4*)&Of[qb * 72 + f4 * 4];
    *(float4*)&O[((size_t)b * SS + q0 + qb) * DQ + f4 * 4] = v;
  }
}

extern "C" void kernel_launch(void* const* d_in, const int* in_sizes, int n_in,
                              void* d_out, int out_size, void* d_ws, size_t ws_size,
                              hipStream_t stream) {
  const float* x  = (const float*)d_in[0];
  const float* Wq = (const float*)d_in[1];
  const float* Wk = (const float*)d_in[2];
  const float* Wv = (const float*)d_in[3];
  short* ws = (short*)d_ws;          // 12.73 MB bf16 scratch
  float* out = (float*)d_out;

  prep_w_kernel<<<288, 256, 0, stream>>>(Wq, Wk, Wv, ws);
  qkv_proj_mfma<<<M_ROWS / 64, 256, 0, stream>>>(x, ws, ws);
  flash_mfma<<<dim3(64, BB), 256, 0, stream>>>(ws, out);
}

// Round 9
// 126.553 us; speedup vs baseline: 1.0024x; 1.0024x over previous
//
#include <hip/hip_runtime.h>
#include <hip/hip_bf16.h>
#include <math.h>

#define BB 16
#define SS 2048
#define DM 384
#define DQ 64
#define M_ROWS (BB * SS)   // 32768

typedef short short8 __attribute__((ext_vector_type(8)));
typedef float f32x4  __attribute__((ext_vector_type(4)));

// ws layout (shorts): Wt [192][384] | Qb [B][S][64] | Kb [B][S][64] | Vt [B][64][S]
#define WT_OFF 0
#define QB_OFF 73728
#define KB_OFF (QB_OFF + M_ROWS * DQ)
#define VT_OFF (KB_OFF + M_ROWS * DQ)

#define QSCALE 0.18033688011112042f   // 0.125 * log2(e); softmax in exp2

__device__ __forceinline__ short f2bf(float f) {
  unsigned u = __builtin_bit_cast(unsigned, f);
  unsigned r = (u + 0x7fffu + ((u >> 16) & 1u)) >> 16;
  return (short)r;
}
__device__ __forceinline__ unsigned pack2bf(float a, float b) {
  return (unsigned)(unsigned short)f2bf(a) |
         ((unsigned)(unsigned short)f2bf(b) << 16);
}
__device__ __forceinline__ void async16(const short* g, short* l) {
  __builtin_amdgcn_global_load_lds(
      (const __attribute__((address_space(1))) unsigned int*)g,
      (__attribute__((address_space(3))) unsigned int*)l, 16, 0, 0);
}

// ---------------------------------------------------------------------------
// Kernel 0: W [384,64] fp32 x3 -> Wt rows [mat*64+n][384] bf16.  288 x 256.
// (validated R4 code)
// ---------------------------------------------------------------------------
__global__ void prep_w_kernel(const float* __restrict__ Wq,
                              const float* __restrict__ Wk,
                              const float* __restrict__ Wv,
                              short* __restrict__ ws) {
  int o = blockIdx.x * 256 + threadIdx.x;        // 0 .. 73727
  int mat = o / (DM * DQ);
  int r = o % (DM * DQ);
  int k = r / DQ, n = r % DQ;                    // coalesced read
  const float* W = (mat == 0) ? Wq : (mat == 1) ? Wk : Wv;
  ws[WT_OFF + mat * (DM * DQ) + n * DM + k] = f2bf(W[k * DQ + n]);
}

// ---------------------------------------------------------------------------
// Kernel 1: QKV projection, bf16 MFMA 16x16x32.  (validated R4 code)
// Block: 64 rows x 192 cols, 256 thr = 4 waves x 16 rows.  grid 512.
// ---------------------------------------------------------------------------
__global__ __launch_bounds__(256) void qkv_proj_mfma(
    const float* __restrict__ x, const short* __restrict__ ws_r,
    short* __restrict__ ws_w) {
  __shared__ short Wtc[192 * 64];   // [row][granule^(row&7)] granules of 8
  __shared__ short Ep[64 * 200];    // epilogue transpose
  const int tid = threadIdx.x;
  const int lane = tid & 63, w = tid >> 6;
  const int cidx = lane & 15, g = lane >> 4;
  const int g8 = g * 8, g4 = g * 4;
  const int sw7 = cidx & 7;
  const int rows0 = blockIdx.x * 64;
  const short* Wt = ws_r + WT_OFF;

  f32x4 acc[12];
  #pragma unroll
  for (int i = 0; i < 12; ++i) acc[i] = (f32x4){0.f, 0.f, 0.f, 0.f};

  const float* xr = x + (size_t)(rows0 + 16 * w + cidx) * DM;

  for (int k0 = 0; k0 < DM; k0 += 64) {
    float4 xc0 = *(const float4*)(xr + k0 + g8);
    float4 xc1 = *(const float4*)(xr + k0 + g8 + 4);
    float4 xc2 = *(const float4*)(xr + k0 + 32 + g8);
    float4 xc3 = *(const float4*)(xr + k0 + 32 + g8 + 4);
    __syncthreads();
    #pragma unroll
    for (int it = 0; it < 6; ++it) {        // 1536 granules of 8 shorts
      int i = it * 256 + tid;
      int row = i >> 3, gr = i & 7;
      const short* src = Wt + row * DM + k0 + ((gr ^ (row & 7)) * 8);
      async16(src, &Wtc[(it * 256 + w * 64) * 8]);
    }
    __syncthreads();   // drains vmcnt: Wtc + x regs ready

    short8 a0, a1;
    a0[0]=f2bf(xc0.x); a0[1]=f2bf(xc0.y); a0[2]=f2bf(xc0.z); a0[3]=f2bf(xc0.w);
    a0[4]=f2bf(xc1.x); a0[5]=f2bf(xc1.y); a0[6]=f2bf(xc1.z); a0[7]=f2bf(xc1.w);
    a1[0]=f2bf(xc2.x); a1[1]=f2bf(xc2.y); a1[2]=f2bf(xc2.z); a1[3]=f2bf(xc2.w);
    a1[4]=f2bf(xc3.x); a1[5]=f2bf(xc3.y); a1[6]=f2bf(xc3.z); a1[7]=f2bf(xc3.w);

    #pragma unroll
    for (int ct = 0; ct < 12; ++ct) {
      int row = ct * 16 + cidx;
      short8 b0 = *(const short8*)&Wtc[row * 64 + ((g ^ sw7) * 8)];
      short8 b1 = *(const short8*)&Wtc[row * 64 + (((g + 4) ^ sw7) * 8)];
      acc[ct] = __builtin_amdgcn_mfma_f32_16x16x32_bf16(a0, b0, acc[ct], 0, 0, 0);
      acc[ct] = __builtin_amdgcn_mfma_f32_16x16x32_bf16(a1, b1, acc[ct], 0, 0, 0);
    }
  }

  __syncthreads();
  const int erow = 16 * w + g4;
  #pragma unroll
  for (int ct = 0; ct < 4; ++ct)
    #pragma unroll
    for (int r = 0; r < 4; ++r) {
      Ep[(erow + r) * 200 + ct * 16 + cidx]       = f2bf(acc[ct][r] * QSCALE);
      Ep[(erow + r) * 200 + 64 + ct * 16 + cidx]  = f2bf(acc[4 + ct][r]);
      Ep[(ct * 16 + cidx) * 200 + 128 + erow + r] = f2bf(acc[8 + ct][r]);
    }
  __syncthreads();

  short* Qb = ws_w + QB_OFF;
  short* Kb = ws_w + KB_OFF;
  short* Vt = ws_w + VT_OFF;
  const int bidx = rows0 >> 11;
  const int srow0 = rows0 & 2047;
  #pragma unroll
  for (int t2 = 0; t2 < 2; ++t2) {
    int i = t2 * 256 + tid;            // 0..511
    int row = i >> 3, gq = i & 7;
    *(short8*)&Qb[(size_t)(rows0 + row) * DQ + gq * 8] =
        *(const short8*)&Ep[row * 200 + gq * 8];
    *(short8*)&Kb[(size_t)(rows0 + row) * DQ + gq * 8] =
        *(const short8*)&Ep[row * 200 + 64 + gq * 8];
    *(short8*)&Vt[(size_t)bidx * (64 * SS) + (size_t)row * SS + srow0 + gq * 8] =
        *(const short8*)&Ep[row * 200 + 128 + gq * 8];   // row = d here
  }
}

// ---------------------------------------------------------------------------
// Kernel 2: causal flash attention, transposed-S MFMA, static-max softmax.
// 64 QUERIES/BLOCK, no key-split: 4 waves x 16 q SHARE each staged K/V
// superstep (halves staging traffic vs 32q blocks).  64-key supersteps,
// K/V double-buffered, one-ahead prefetch.  Per-wave Ps; no combine epilogue.
// LDS 40 KB -> 4 blocks/CU.  grid (32, 16) = 512 blocks x 256 thr.
// ---------------------------------------------------------------------------
__global__ __launch_bounds__(256, 4) void flash_mfma(
    const short* __restrict__ ws, float* __restrict__ O) {
  __shared__ short smem[20480];   // KsA 0 | KsB 4096 | VtsA 8192 | VtsB 12288 | Ps 16384
  const int b = blockIdx.y;
  const int qx = blockIdx.x;                // 0..31
  const int qt = (b < 8) ? (31 - qx) : qx;  // causal balance pairing
  const int q0 = qt * 64;
  const int tid = threadIdx.x;
  const int lane = tid & 63, w = tid >> 6;
  const int cidx = lane & 15, g = lane >> 4;
  const int g8 = g * 8, g4 = g * 4;
  const int sw7 = cidx & 7;
  short* Ps = smem + 16384 + w * 1024;      // [16 q][64 k] swizzled, per wave

  const short* Qb = ws + QB_OFF + (size_t)b * SS * DQ;
  const short* Kb = ws + KB_OFF + (size_t)b * SS * DQ;
  const short* Vt = ws + VT_OFF + (size_t)b * 64 * SS;

  const int qrow = q0 + w * 16;             // wave w owns queries qrow..qrow+15
  const int qglob = qrow + cidx;            // this lane's query
  short8 qf0 = *(const short8*)&Qb[(size_t)qglob * DQ + g8];
  short8 qf1 = *(const short8*)&Qb[(size_t)qglob * DQ + 32 + g8];

  // staging: round r covers rows r*32..r*32+31; (row+32)&7 == row&7
  const int srow = tid >> 3, sgr = tid & 7;
  const int ssw = (sgr ^ (srow & 7)) * 8;
  const short* kb0 = Kb + (size_t)srow * DQ + ssw;
  const short* kb1 = Kb + (size_t)(srow + 32) * DQ + ssw;
  const short* vb0 = Vt + (size_t)srow * SS + ssw;
  const short* vb1 = Vt + (size_t)(srow + 32) * SS + ssw;
  const int dst0 = (w * 64) * 8, dst1 = (256 + w * 64) * 8;

  f32x4 o[4];
  #pragma unroll
  for (int i = 0; i < 4; ++i) o[i] = (f32x4){0.f, 0.f, 0.f, 0.f};
  float l = 0.f;

  const int nss = qt + 1;                   // 64-key supersteps

  // preamble: superstep 0 -> buffer 0
  async16(kb0, &smem[dst0]);
  async16(kb1, &smem[dst1]);
  async16(vb0, &smem[8192 + dst0]);
  async16(vb1, &smem[8192 + dst1]);

  for (int ssi = 0; ssi < nss; ++ssi) {
    __syncthreads();   // drains prefetch of ss `ssi` (issued last iteration)

    {   // prefetch ss+1 into the other buffer (clamped to q0: always in-bounds)
      int nb = (ssi + 1) * 64;
      if (nb > q0) nb = q0;
      const int nbuf = ((ssi + 1) & 1) * 4096;
      const size_t koff = (size_t)nb * DQ;
      async16(kb0 + koff, &smem[nbuf + dst0]);
      async16(kb1 + koff, &smem[nbuf + dst1]);
      async16(vb0 + nb, &smem[8192 + nbuf + dst0]);
      async16(vb1 + nb, &smem[8192 + nbuf + dst1]);
    }

    const short* Kc = smem + (ssi & 1) * 4096;
    const short* Vc = smem + 8192 + (ssi & 1) * 4096;
    const int kbase = ssi * 64;

    // S^T = K Q^T : 4 key-tiles of 16
    f32x4 sc[4];
    #pragma unroll
    for (int ct = 0; ct < 4; ++ct) {
      int krow = ct * 16 + cidx;            // krow&7 == sw7
      short8 kf0 = *(const short8*)&Kc[krow * 64 + ((g ^ sw7) * 8)];
      short8 kf1 = *(const short8*)&Kc[krow * 64 + (((g + 4) ^ sw7) * 8)];
      f32x4 a = (f32x4){0.f, 0.f, 0.f, 0.f};
      a = __builtin_amdgcn_mfma_f32_16x16x32_bf16(kf0, qf0, a, 0, 0, 0);
      a = __builtin_amdgcn_mfma_f32_16x16x32_bf16(kf1, qf1, a, 0, 0, 0);
      sc[ct] = a;
    }
    if (ssi == nss - 1) {                   // diagonal tile: mask key > q
      #pragma unroll
      for (int ct = 0; ct < 4; ++ct) {
        int key = kbase + ct * 16 + g4;
        #pragma unroll
        for (int r = 0; r < 4; ++r)
          if (key + r > qglob) sc[ct][r] = -1e30f;
      }
    }
    // static-max softmax: p = 2^s, per-lane l, no rescale
    #pragma unroll
    for (int ct = 0; ct < 4; ++ct) {
      #pragma unroll
      for (int r = 0; r < 4; ++r) {
        float p = __builtin_amdgcn_exp2f(sc[ct][r]);
        sc[ct][r] = p;
        l += p;
      }
      // P^T -> Ps[q][key] (wave-local, swizzled), one b64 write per ct
      int gb = ct * 2 + (g >> 1);
      uint2 pk;
      pk.x = pack2bf(sc[ct][0], sc[ct][1]);
      pk.y = pack2bf(sc[ct][2], sc[ct][3]);
      *(uint2*)&Ps[cidx * 64 + ((gb ^ sw7) * 8) + (g & 1) * 4] = pk;
    }
    // O^T += V^T P^T  (K=64 keys -> 2 x K32 per d-tile)
    #pragma unroll
    for (int ks = 0; ks < 2; ++ks) {
      short8 pf = *(const short8*)&Ps[cidx * 64 + (((ks * 4 + g) ^ sw7) * 8)];
      #pragma unroll
      for (int dt = 0; dt < 4; ++dt) {
        int vrow = dt * 16 + cidx;          // vrow&7 == sw7
        short8 vf = *(const short8*)&Vc[vrow * 64 + (((ks * 4 + g) ^ sw7) * 8)];
        o[dt] = __builtin_amdgcn_mfma_f32_16x16x32_bf16(vf, pf, o[dt], 0, 0, 0);
      }
    }
  }

  // query qglob's scores sit in lanes {cidx, cidx+16, cidx+32, cidx+48}
  l += __shfl_xor(l, 16);
  l += __shfl_xor(l, 32);
  const float inv = 1.0f / l;

  // direct store: lane holds d = dt*16 + g4 + r for query qglob
  float* op = O + ((size_t)b * SS + qglob) * DQ;
  #pragma unroll
  for (int dt = 0; dt < 4; ++dt) {
    float4 v = make_float4(o[dt][0] * inv, o[dt][1] * inv,
                           o[dt][2] * inv, o[dt][3] * inv);
    *(float4*)&op[dt * 16 + g4] = v;
  }
}

extern "C" void kernel_launch(void* const* d_in, const int* in_sizes, int n_in,
                              void* d_out, int out_size, void* d_ws, size_t ws_size,
                              hipStream_t stream) {
  const float* x  = (const float*)d_in[0];
  const float* Wq = (const float*)d_in[1];
  const float* Wk = (const float*)d_in[2];
  const float* Wv = (const float*)d_in[3];
  short* ws = (short*)d_ws;          // 12.73 MB bf16 scratch
  float* out = (float*)d_out;

  prep_w_kernel<<<288, 256, 0, stream>>>(Wq, Wk, Wv, ws);
  qkv_proj_mfma<<<M_ROWS / 64, 256, 0, stream>>>(x, ws, ws);
  flash_mfma<<<dim3(32, BB), 256, 0, stream>>>(ws, out);
}